// Round 6
// baseline (32.301 us; speedup 1.0000x reference)
//
#include <hip/hip_runtime.h>

// Sobel3D: data [4,1,256,256,64] f32 -> out [4,1,256,256,64] f32 (0/1).
// out = 1 iff >=2 of the 3 directional Sobel gradients are nonzero.
//
// Separable decomposition (cross-correlation, SAME zero padding):
//   per (d,h) row:  S[i] = x[i-1]+2x[i]+x[i+1],  D[i] = x[i-1]-x[i+1]
//   per plane d:    ds = D(h-1)+D(h)+D(h+1), ss = S(h-1)+S(h)+S(h+1),
//                   sd = S(h-1)-S(h+1)
//   Gx = ds(d-1)+2*ds(d)+ds(d+1); Gy = ss(d-1)-ss(d+1); Gz = sd(d-1)+sd(d)+sd(d+1)
//
// R6 = R5 with the nontemporal store fixed (native clang vector type).
//  - no LDS/barriers; thread owns (b,h,w0..w0+3), 8 output planes, unrolled.
//  - w-halo via DPP row_shr:1/row_shl:1 with bound_ctrl zero-fill.
//  - ring of 4 raw plane buffers, depth-3 prefetch: at every consume point,
//    3 planes (9 float4 loads) are in flight.
//  - DC=8: d-halo redundancy 1.25x.
//  - nontemporal output stores: keep the write stream from evicting the
//    3x-reread input out of L2/L3.

constexpr int DDIM = 256;
constexpr int HDIM = 256;
constexpr int WWID = 64;
constexpr int DC   = 8;    // output d-planes per block
constexpr int HT   = 8;    // h rows per block (2 waves)

typedef float vfloat4 __attribute__((ext_vector_type(4)));   // clang-native

struct P3  { float ds[4], ss[4], sd[4]; };
struct Raw { float4 a, b, c; };

__device__ __forceinline__ float dpp_up1(float v) {   // lane n <- lane n-1 (16-lane row), edge->0
  return __builtin_bit_cast(float, __builtin_amdgcn_update_dpp(
      0, __builtin_bit_cast(int, v), 0x111, 0xf, 0xf, true));  // row_shr:1
}
__device__ __forceinline__ float dpp_dn1(float v) {   // lane n <- lane n+1 (16-lane row), edge->0
  return __builtin_bit_cast(float, __builtin_amdgcn_update_dpp(
      0, __builtin_bit_cast(int, v), 0x101, 0xf, 0xf, true));  // row_shl:1
}

__global__ __launch_bounds__(128) void sobel3d_kernel(
    const float* __restrict__ in, float* __restrict__ out) {
  const int lane = threadIdx.x;          // 0..63
  const int wg   = lane & 15;            // w-group within row (16 x float4 = row)
  const int hs   = lane >> 4;            // h-sub within wave
  const int w0   = wg * 4;
  const int h    = blockIdx.x * HT + threadIdx.y * 4 + hs;
  const int d0   = blockIdx.y * DC;
  const int b    = blockIdx.z;

  const size_t plane = (size_t)HDIM * WWID;   // 16384 floats
  const float* src = in  + (size_t)b * DDIM * plane;
  float*       dst = out + (size_t)b * DDIM * plane;

  const size_t offb = (size_t)h * WWID + w0;  // this thread's row base
  const bool va = (h > 0);                    // h-1 valid
  const bool vc = (h + 1 < HDIM);             // h+1 valid

  auto loadPlane = [&](int d, Raw& r) {
    if ((unsigned)d < (unsigned)DDIM) {
      const float* p = src + (size_t)d * plane;
      r.b = *(const float4*)(p + offb);
      r.a = va ? *(const float4*)(p + offb - WWID) : float4{0.f, 0.f, 0.f, 0.f};
      r.c = vc ? *(const float4*)(p + offb + WWID) : float4{0.f, 0.f, 0.f, 0.f};
    } else {
      r.a = r.b = r.c = float4{0.f, 0.f, 0.f, 0.f};
    }
  };

  // row partials S (1,2,1) and D (1,0,-1) at the 4 output w positions
  auto rowSD = [&](float4 v, float* S, float* D) {
    const float x1 = (v.x == 255.f) ? 0.f : v.x;   // reference where()
    const float x2 = (v.y == 255.f) ? 0.f : v.y;
    const float x3 = (v.z == 255.f) ? 0.f : v.z;
    const float x4 = (v.w == 255.f) ? 0.f : v.w;
    const float xm = dpp_up1(x4);   // x[w0-1] (0 at w-edge)
    const float xp = dpp_dn1(x1);   // x[w0+4] (0 at w-edge)
    const float x[6] = {xm, x1, x2, x3, x4, xp};
    #pragma unroll
    for (int i = 0; i < 4; ++i) {
      S[i] = fmaf(2.f, x[i + 1], x[i]) + x[i + 2];
      D[i] = x[i] - x[i + 2];
    }
  };

  auto partials = [&](const Raw& r, P3& o) {
    float Sa[4], Da[4], Sb[4], Db[4], Sc[4], Dc[4];
    rowSD(r.a, Sa, Da);
    rowSD(r.b, Sb, Db);
    rowSD(r.c, Sc, Dc);
    #pragma unroll
    for (int i = 0; i < 4; ++i) {
      o.ds[i] = Da[i] + Db[i] + Dc[i];
      o.ss[i] = Sa[i] + Sb[i] + Sc[i];
      o.sd[i] = Sa[i] - Sc[i];
    }
  };

  auto emit = [&](int d, const P3& p, const P3& c, const P3& n) {
    vfloat4 o;
    #pragma unroll
    for (int i = 0; i < 4; ++i) {
      const float Gx = fmaf(2.f, c.ds[i], p.ds[i]) + n.ds[i];
      const float Gy = p.ss[i] - n.ss[i];
      const float Gz = p.sd[i] + c.sd[i] + n.sd[i];
      const int cnt = (Gx != 0.f) + (Gy != 0.f) + (Gz != 0.f);
      o[i] = (cnt >= 2) ? 1.f : 0.f;
    }
    __builtin_nontemporal_store(o, (vfloat4*)(dst + (size_t)d * plane + offb));
  };

  Raw A, B, C, D;          // 4-buffer raw-plane ring
  P3 p0, p1, p2;           // 3-slot partials ring

  // depth-3 software pipeline over planes d0-1 .. d0+8 (10 loads, 8 outputs)
  loadPlane(d0 - 1, A);
  loadPlane(d0,     B);
  loadPlane(d0 + 1, C);
  loadPlane(d0 + 2, D);
  partials(A, p0);  loadPlane(d0 + 3, A);
  partials(B, p1);  loadPlane(d0 + 4, B);
  partials(C, p2);  emit(d0,     p0, p1, p2);  loadPlane(d0 + 5, C);
  partials(D, p0);  emit(d0 + 1, p1, p2, p0);  loadPlane(d0 + 6, D);
  partials(A, p1);  emit(d0 + 2, p2, p0, p1);  loadPlane(d0 + 7, A);
  partials(B, p2);  emit(d0 + 3, p0, p1, p2);  loadPlane(d0 + 8, B);
  partials(C, p0);  emit(d0 + 4, p1, p2, p0);
  partials(D, p1);  emit(d0 + 5, p2, p0, p1);
  partials(A, p2);  emit(d0 + 6, p0, p1, p2);
  partials(B, p0);  emit(d0 + 7, p1, p2, p0);
}

extern "C" void kernel_launch(void* const* d_in, const int* in_sizes, int n_in,
                              void* d_out, int out_size, void* d_ws, size_t ws_size,
                              hipStream_t stream) {
  const float* data = (const float*)d_in[0];
  // d_in[1] = Sobel weights — fixed by the reference, folded into the kernel.
  float* out = (float*)d_out;
  dim3 grid(HDIM / HT, DDIM / DC, 4);   // (32, 32, 4) = 4096 blocks
  dim3 block(WWID, 2);                  // 128 threads = 2 waves
  sobel3d_kernel<<<grid, block, 0, stream>>>(data, out);
}

// Round 7
// 31.684 us; speedup vs baseline: 1.0195x; 1.0195x over previous
//
#include <hip/hip_runtime.h>

// Sobel3D: data [4,1,256,256,64] f32 -> out [4,1,256,256,64] f32 (0/1).
// out = 1 iff >=2 of the 3 directional Sobel gradients are nonzero.
//
// Separable decomposition (cross-correlation, SAME zero padding):
//   per (d,h) row:  S[i] = x[i-1]+2x[i]+x[i+1],  D[i] = x[i-1]-x[i+1]
//   per plane d:    ds = D(h-1)+D(h)+D(h+1), ss = S(h-1)+S(h)+S(h+1),
//                   sd = S(h-1)-S(h+1)
//   Gx = ds(d-1)+2*ds(d)+ds(d+1); Gy = ss(d-1)-ss(d+1); Gz = sd(d-1)+sd(d)+sd(d+1)
//
// R7 design (from R4/R6 post-mortem):
//  - thread tile = 2 h-rows x 4 w: row partials S/D computed 2x redundantly
//    (was 3x), sliding-window sharing in the h-combine, 26% fewer VMEM instrs.
//  - plain stores (nontemporal regressed in R6 vs R4).
//  - depth-2 raw-plane ring (2 planes x 4 loads in flight at every consume).
//  - w-halo via DPP row_shr:1/row_shl:1, bound_ctrl zero-fill.

constexpr int DDIM = 256;
constexpr int HDIM = 256;
constexpr int WWID = 64;
constexpr int DC   = 8;    // output d-planes per block
constexpr int HT   = 16;   // h rows per block (2 waves x 8)

typedef float vfloat4 __attribute__((ext_vector_type(4)));

struct Raw { float4 a, b, c, d; };   // rows hb-1, hb, hb+1, hb+2 of one plane
struct P3  { float ds0[4], ds1[4], ss0[4], ss1[4], sd0[4], sd1[4]; };

__device__ __forceinline__ float dpp_up1(float v) {   // lane n <- lane n-1 (16-lane row), edge->0
  return __builtin_bit_cast(float, __builtin_amdgcn_update_dpp(
      0, __builtin_bit_cast(int, v), 0x111, 0xf, 0xf, true));  // row_shr:1
}
__device__ __forceinline__ float dpp_dn1(float v) {   // lane n <- lane n+1 (16-lane row), edge->0
  return __builtin_bit_cast(float, __builtin_amdgcn_update_dpp(
      0, __builtin_bit_cast(int, v), 0x101, 0xf, 0xf, true));  // row_shl:1
}

__global__ __launch_bounds__(128) void sobel3d_kernel(
    const float* __restrict__ in, float* __restrict__ out) {
  const int lane = threadIdx.x;          // 0..63
  const int wg   = lane & 15;            // w-group within row (16 x float4 = row)
  const int hs   = lane >> 4;            // h-sub within wave (0..3)
  const int w0   = wg * 4;
  const int hb   = blockIdx.x * HT + threadIdx.y * 8 + hs * 2;  // first of 2 rows
  const int d0   = blockIdx.y * DC;
  const int b    = blockIdx.z;

  const size_t plane = (size_t)HDIM * WWID;   // 16384 floats
  const float* src = in  + (size_t)b * DDIM * plane;
  float*       dst = out + (size_t)b * DDIM * plane;

  const size_t offb = (size_t)hb * WWID + w0;  // row hb base
  const bool va = (hb > 0);                    // hb-1 valid
  const bool vd = (hb + 2 < HDIM);             // hb+2 valid (hb,hb+1 always)

  auto loadPlane = [&](int d, Raw& r) {
    if ((unsigned)d < (unsigned)DDIM) {
      const float* p = src + (size_t)d * plane;
      r.b = *(const float4*)(p + offb);
      r.c = *(const float4*)(p + offb + WWID);
      r.a = va ? *(const float4*)(p + offb - WWID)     : float4{0.f, 0.f, 0.f, 0.f};
      r.d = vd ? *(const float4*)(p + offb + 2 * WWID) : float4{0.f, 0.f, 0.f, 0.f};
    } else {
      r.a = r.b = r.c = r.d = float4{0.f, 0.f, 0.f, 0.f};
    }
  };

  // row partials S (1,2,1) and D (1,0,-1) at the 4 output w positions
  auto rowSD = [&](float4 v, float* S, float* D) {
    const float x1 = (v.x == 255.f) ? 0.f : v.x;   // reference where()
    const float x2 = (v.y == 255.f) ? 0.f : v.y;
    const float x3 = (v.z == 255.f) ? 0.f : v.z;
    const float x4 = (v.w == 255.f) ? 0.f : v.w;
    const float xm = dpp_up1(x4);   // x[w0-1] (0 at w-edge)
    const float xp = dpp_dn1(x1);   // x[w0+4] (0 at w-edge)
    const float x[6] = {xm, x1, x2, x3, x4, xp};
    #pragma unroll
    for (int i = 0; i < 4; ++i) {
      S[i] = fmaf(2.f, x[i + 1], x[i]) + x[i + 2];
      D[i] = x[i] - x[i + 2];
    }
  };

  auto partials = [&](const Raw& r, P3& o) {
    float Sa[4], Da[4], Sb[4], Db[4], Sc[4], Dc[4], Sd[4], Dd[4];
    rowSD(r.a, Sa, Da);
    rowSD(r.b, Sb, Db);
    rowSD(r.c, Sc, Dc);
    rowSD(r.d, Sd, Dd);
    #pragma unroll
    for (int i = 0; i < 4; ++i) {
      const float D12 = Db[i] + Dc[i];
      const float S12 = Sb[i] + Sc[i];
      o.ds0[i] = Da[i] + D12;   // out row hb
      o.ds1[i] = D12 + Dd[i];   // out row hb+1
      o.ss0[i] = Sa[i] + S12;
      o.ss1[i] = S12 + Sd[i];
      o.sd0[i] = Sa[i] - Sc[i];
      o.sd1[i] = Sb[i] - Sd[i];
    }
  };

  auto emit = [&](int d, const P3& p, const P3& c, const P3& n) {
    vfloat4 o0, o1;
    #pragma unroll
    for (int i = 0; i < 4; ++i) {
      {
        const float Gx = fmaf(2.f, c.ds0[i], p.ds0[i]) + n.ds0[i];
        const float Gy = p.ss0[i] - n.ss0[i];
        const float Gz = p.sd0[i] + c.sd0[i] + n.sd0[i];
        const int cnt = (Gx != 0.f) + (Gy != 0.f) + (Gz != 0.f);
        o0[i] = (cnt >= 2) ? 1.f : 0.f;
      }
      {
        const float Gx = fmaf(2.f, c.ds1[i], p.ds1[i]) + n.ds1[i];
        const float Gy = p.ss1[i] - n.ss1[i];
        const float Gz = p.sd1[i] + c.sd1[i] + n.sd1[i];
        const int cnt = (Gx != 0.f) + (Gy != 0.f) + (Gz != 0.f);
        o1[i] = (cnt >= 2) ? 1.f : 0.f;
      }
    }
    float* q = dst + (size_t)d * plane + offb;
    *(vfloat4*)q = o0;
    *(vfloat4*)(q + WWID) = o1;
  };

  Raw A, B, C;             // 3-buffer raw-plane ring (depth-2 prefetch)
  P3 p0, p1, p2;           // 3-slot partials ring

  // software pipeline over planes d0-1 .. d0+8 (10 plane-loads, 8 outputs)
  loadPlane(d0 - 1, A);
  loadPlane(d0,     B);
  loadPlane(d0 + 1, C);
  partials(A, p0);  loadPlane(d0 + 2, A);
  partials(B, p1);  loadPlane(d0 + 3, B);
  partials(C, p2);  emit(d0,     p0, p1, p2);  loadPlane(d0 + 4, C);
  partials(A, p0);  emit(d0 + 1, p1, p2, p0);  loadPlane(d0 + 5, A);
  partials(B, p1);  emit(d0 + 2, p2, p0, p1);  loadPlane(d0 + 6, B);
  partials(C, p2);  emit(d0 + 3, p0, p1, p2);  loadPlane(d0 + 7, C);
  partials(A, p0);  emit(d0 + 4, p1, p2, p0);  loadPlane(d0 + 8, A);
  partials(B, p1);  emit(d0 + 5, p2, p0, p1);
  partials(C, p2);  emit(d0 + 6, p0, p1, p2);
  partials(A, p0);  emit(d0 + 7, p1, p2, p0);
}

extern "C" void kernel_launch(void* const* d_in, const int* in_sizes, int n_in,
                              void* d_out, int out_size, void* d_ws, size_t ws_size,
                              hipStream_t stream) {
  const float* data = (const float*)d_in[0];
  // d_in[1] = Sobel weights — fixed by the reference, folded into the kernel.
  float* out = (float*)d_out;
  dim3 grid(HDIM / HT, DDIM / DC, 4);   // (16, 32, 4) = 2048 blocks
  dim3 block(WWID, 2);                  // 128 threads = 2 waves
  sobel3d_kernel<<<grid, block, 0, stream>>>(data, out);
}